// Round 8
// baseline (372.923 us; speedup 1.0000x reference)
//
#include <hip/hip_runtime.h>

// NT-Xent loss, B=4096, D=256, N=8192, T=0.5
// loss = [ sum_r ( log(sum_{c!=r} exp(2*f_r.f_c)) - 2*f_r.f_pos(r) ) ] / N^2
// v8: symmetric upper-triangle (528 blocks, half the work; off-diag blocks
// emit row-sums AND col-sums) + F8 stored in MFMA-fragment-panel order so
// staging is a contiguous 16KB copy (fully coalesced) and A-loads coalesce.
// v6's proven 2-phase dbuf sync, MX-fp8 32x32x64 unit scales, exp2 fold.

#define B_ROWS 4096
#define DIM 256
#define NTOT 8192
#define NTILEBLK 32      // 32 tiles of 256 -> slots
#define TILE_COLS 64
#define NTILE 4          // 4 x 64 cols = 256-col tile
#define SCALE_IN 1.69864360f   // sqrt(2*log2(e)): acc = 2*log2e*dot, exp2(acc)=exp(2 dot)

typedef int i32x4 __attribute__((ext_vector_type(4)));
typedef int i32x8 __attribute__((ext_vector_type(8)));
typedef float f32x16 __attribute__((ext_vector_type(16)));
typedef __attribute__((address_space(1))) const unsigned int gas_uint;
typedef __attribute__((address_space(3))) unsigned int las_uint;

__device__ __forceinline__ float wave_reduce_add(float v) {
#pragma unroll
    for (int m = 1; m < 64; m <<= 1) v += __shfl_xor(v, m, 64);
    return v;
}

// Fragment-panel layout: panel = row>>6 (16KB each). Within panel, 16B chunk
// index = ks*256 + cblk*128 + h*64 + l, where row = cblk*32 + (l&31),
// k = ks*64 + (l>>5)*32 + h*16. Serves LDS staging (linear copy), A-frags,
// and B-frags identically (sim = F*F^T: both operands are F rows).

// K1: 4 waves/block, one row-pair per wave. Normalize (fp32), write fp8 feats
// (scaled by SCALE_IN) into fragment-panel layout; exact fp32 positive sims.
__global__ __launch_bounds__(256) void k_norm(const float* __restrict__ zi,
                                              const float* __restrict__ zj,
                                              unsigned char* __restrict__ F8,
                                              float* __restrict__ pos_sim) {
    const int wave = threadIdx.x >> 6;
    const int lane = threadIdx.x & 63;
    const int r = blockIdx.x * 4 + wave;
    const float4 vi = reinterpret_cast<const float4*>(zi + (size_t)r * DIM)[lane];
    const float4 vj = reinterpret_cast<const float4*>(zj + (size_t)r * DIM)[lane];
    float si = vi.x * vi.x + vi.y * vi.y + vi.z * vi.z + vi.w * vi.w;
    float sj = vj.x * vj.x + vj.y * vj.y + vj.z * vj.z + vj.w * vj.w;
    si = wave_reduce_add(si);
    sj = wave_reduce_add(sj);
    const float ri = SCALE_IN / sqrtf(si);
    const float rj = SCALE_IN / sqrtf(sj);
    const float a0 = vi.x * ri, a1 = vi.y * ri, a2 = vi.z * ri, a3 = vi.w * ri;
    const float b0 = vj.x * rj, b1 = vj.y * rj, b2 = vj.z * rj, b3 = vj.w * rj;
    const float inv2 = 1.0f / (SCALE_IN * SCALE_IN);
    float dot = (a0 * b0 + a1 * b1 + a2 * b2 + a3 * b3) * inv2;
    dot = wave_reduce_add(dot);
    int pa = __builtin_amdgcn_cvt_pk_fp8_f32(a0, a1, 0, false);
    pa = __builtin_amdgcn_cvt_pk_fp8_f32(a2, a3, pa, true);
    int pb = __builtin_amdgcn_cvt_pk_fp8_f32(b0, b1, 0, false);
    pb = __builtin_amdgcn_cvt_pk_fp8_f32(b2, b3, pb, true);
    // this lane holds k = lane*4 .. lane*4+3 of its row -> frag address:
    const int ks = lane >> 4;
    const int k32 = (lane >> 3) & 1;
    const int h = (lane >> 2) & 1;
    const int b4 = (lane & 3) * 4;
    const size_t inner = (size_t)ks * 4096 + h * 1024 + 32 * k32 * 16 + b4;
    {
        const size_t addr = (size_t)(r >> 6) * 16384 + ((r >> 5) & 1) * 2048
                            + (r & 31) * 16 + inner;
        *reinterpret_cast<int*>(F8 + addr) = pa;
    }
    {
        const int r2 = r + B_ROWS;
        const size_t addr = (size_t)(r2 >> 6) * 16384 + ((r2 >> 5) & 1) * 2048
                            + (r2 & 31) * 16 + inner;
        *reinterpret_cast<int*>(F8 + addr) = pb;
    }
    if (lane == 0) {
        const float ps = 2.0f * dot;
        pos_sim[r] = ps;
        pos_sim[r + B_ROWS] = ps;
    }
}

// K2: upper-triangle tile (i,j), 256x256 per block. 8 waves x 32 rows.
// Row-sums -> Spart[j][rows of i]; col-sums (off-diag) -> Spart[i][cols of j].
__global__ __launch_bounds__(512, 4) void k_simsum(const unsigned char* __restrict__ F8,
                                                   float* __restrict__ Spart) {
    __shared__ unsigned char Bsm[2][16384];
    // triangular decode (uniform scalar)
    int rem = blockIdx.x, ti = 0;
    while (rem >= NTILEBLK - ti) { rem -= NTILEBLK - ti; ++ti; }
    const int tj = ti + rem;
    const bool isdiag = (ti == tj);

    const int tid = threadIdx.x;
    const int wave = tid >> 6;
    const int lane = tid & 63;
    const int c32 = lane & 31;
    const int l5 = lane >> 5;

    const int wrow0 = ti * 256 + wave * 32;
    const int col0 = tj * 256;

    // A fragments (frag-panel layout, coalesced): row = wrow0 + c32
    i32x8 a[4];
    {
        const unsigned char* apan = F8 + (size_t)(wrow0 >> 6) * 16384
                                    + ((wrow0 >> 5) & 1) * 2048 + lane * 16;
#pragma unroll
        for (int ks = 0; ks < 4; ++ks) {
            const i32x4 lo = *reinterpret_cast<const i32x4*>(apan + ks * 4096);
            const i32x4 hi = *reinterpret_cast<const i32x4*>(apan + ks * 4096 + 1024);
            a[ks] = __builtin_shufflevector(lo, hi, 0, 1, 2, 3, 4, 5, 6, 7);
        }
    }

    // stage tile t: contiguous 16KB panel copy (1024 chunks / 512 thr)
    auto stage = [&](int buf, int t) {
        const unsigned char* src = F8 + (size_t)(tj * 4 + t) * 16384;
#pragma unroll
        for (int i2 = 0; i2 < 2; ++i2) {
            __builtin_amdgcn_global_load_lds((gas_uint*)(src + (i2 * 512 + tid) * 16),
                                             (las_uint*)(&Bsm[buf][(i2 * 512 + wave * 64) * 16]),
                                             16, 0, 0);
        }
    };

    float sums[16];
#pragma unroll
    for (int g = 0; g < 16; ++g) sums[g] = 0.0f;
    float csum[NTILE][2];
#pragma unroll
    for (int t = 0; t < NTILE; ++t) { csum[t][0] = 0.0f; csum[t][1] = 0.0f; }

    stage(0, 0);
    asm volatile("s_waitcnt vmcnt(0)");
    __syncthreads();

#pragma unroll
    for (int t = 0; t < NTILE; ++t) {
        const int buf = t & 1;
        if (t + 1 < NTILE) stage(buf ^ 1, t + 1);

        f32x16 acc0 = {};
        f32x16 acc1 = {};
#pragma unroll
        for (int ks = 0; ks < 4; ++ks) {
            const unsigned char* base = &Bsm[buf][ks * 4096 + lane * 16];
            const i32x8 b0 = __builtin_shufflevector(
                *reinterpret_cast<const i32x4*>(base),
                *reinterpret_cast<const i32x4*>(base + 1024), 0, 1, 2, 3, 4, 5, 6, 7);
            const i32x8 b1 = __builtin_shufflevector(
                *reinterpret_cast<const i32x4*>(base + 2048),
                *reinterpret_cast<const i32x4*>(base + 3072), 0, 1, 2, 3, 4, 5, 6, 7);
            acc0 = __builtin_amdgcn_mfma_scale_f32_32x32x64_f8f6f4(
                a[ks], b0, acc0, 0, 0, 0, 0x7F7F7F7F, 0, 0x7F7F7F7F);
            acc1 = __builtin_amdgcn_mfma_scale_f32_32x32x64_f8f6f4(
                a[ks], b1, acc1, 0, 0, 0, 0x7F7F7F7F, 0, 0x7F7F7F7F);
        }

        const int cb = col0 + t * TILE_COLS;
        const bool d0 = isdiag && (wrow0 == cb);
        const bool d1 = isdiag && (wrow0 == cb + 32);
#pragma unroll
        for (int g = 0; g < 16; ++g) {
            const int rowid = (g & 3) + 8 * (g >> 2) + 4 * l5;
            float e0 = exp2f(acc0[g]);
            float e1 = exp2f(acc1[g]);
            if (d0 && rowid == c32) e0 = 0.0f;
            if (d1 && rowid == c32) e1 = 0.0f;
            sums[g] += e0 + e1;
            csum[t][0] += e0;
            csum[t][1] += e1;
        }

        asm volatile("s_waitcnt vmcnt(0)");
        __syncthreads();
    }

    // row-sums: fold across the 32 lanes holding each row's columns
#pragma unroll
    for (int g = 0; g < 16; ++g) {
        float s = sums[g];
        s += __shfl_xor(s, 1, 64);
        s += __shfl_xor(s, 2, 64);
        s += __shfl_xor(s, 4, 64);
        s += __shfl_xor(s, 8, 64);
        s += __shfl_xor(s, 16, 64);
        if (c32 == 0) {
            const int row = wrow0 + (g & 3) + 8 * (g >> 2) + 4 * l5;
            Spart[(size_t)tj * NTOT + row] = s;
        }
    }

    // col-sums (off-diag): fold l5 halves, reduce across 8 waves via LDS
    if (!isdiag) {
        float* cl = reinterpret_cast<float*>(&Bsm[0][0]);   // [8][256] floats
#pragma unroll
        for (int t = 0; t < NTILE; ++t) {
            const float c0f = csum[t][0] + __shfl_xor(csum[t][0], 32, 64);
            const float c1f = csum[t][1] + __shfl_xor(csum[t][1], 32, 64);
            const float v = (l5 == 0) ? c0f : c1f;
            cl[wave * 256 + t * 64 + l5 * 32 + c32] = v;
        }
        __syncthreads();
        if (tid < 256) {
            float tot = 0.0f;
#pragma unroll
            for (int w = 0; w < 8; ++w) tot += cl[w * 256 + tid];
            Spart[(size_t)ti * NTOT + col0 + tid] = tot;
        }
    }
}

// K3a: 32 blocks x 256 thr, one row each: S = sum slots, local = log(S)-pos.
__global__ __launch_bounds__(256) void k_reduce(const float* __restrict__ Spart,
                                                const float* __restrict__ pos_sim,
                                                float* __restrict__ Bpart) {
    __shared__ float red[4];
    const int r = blockIdx.x * 256 + threadIdx.x;
    float s = 0.0f;
#pragma unroll
    for (int c = 0; c < NTILEBLK; ++c) s += Spart[(size_t)c * NTOT + r];
    float local = logf(s) - pos_sim[r];
    local = wave_reduce_add(local);
    if ((threadIdx.x & 63) == 0) red[threadIdx.x >> 6] = local;
    __syncthreads();
    if (threadIdx.x == 0) Bpart[blockIdx.x] = red[0] + red[1] + red[2] + red[3];
}

// K3b: single wave folds 32 block partials.
__global__ void k_fin(const float* __restrict__ Bpart, float* __restrict__ out) {
    float v = (threadIdx.x < 32) ? Bpart[threadIdx.x] : 0.0f;
    v = wave_reduce_add(v);
    if (threadIdx.x == 0) out[0] = v / ((float)NTOT * (float)NTOT);
}

extern "C" void kernel_launch(void* const* d_in, const int* in_sizes, int n_in,
                              void* d_out, int out_size, void* d_ws, size_t ws_size,
                              hipStream_t stream) {
    (void)in_sizes; (void)n_in; (void)out_size; (void)ws_size;
    const float* zi = (const float*)d_in[0];
    const float* zj = (const float*)d_in[1];
    float* out = (float*)d_out;

    char* ws = (char*)d_ws;
    unsigned char* F8 = (unsigned char*)ws;                     // 2 MiB fp8 feats, frag-panel order
    float* pos_sim = (float*)(ws + 2097152);                    // 32 KiB
    float* Spart = (float*)(ws + 2097152 + 65536);              // 1 MiB (32 slots x 8192)
    float* Bpart = (float*)(ws + 2097152 + 65536 + 1048576);    // 128 B

    k_norm<<<B_ROWS / 4, 256, 0, stream>>>(zi, zj, F8, pos_sim);
    k_simsum<<<(NTILEBLK * (NTILEBLK + 1)) / 2, 512, 0, stream>>>(F8, Spart);
    k_reduce<<<NTOT / 256, 256, 0, stream>>>(Spart, pos_sim, Bpart);
    k_fin<<<1, 64, 0, stream>>>(Bpart, out);
}

// Round 9
// 50.276 us; speedup vs baseline: 7.4176x; 7.4176x over previous
//
#include <hip/hip_runtime.h>

// NT-Xent loss, B=4096, D=256, N=8192, T=0.5
// loss = [ sum_r ( log(sum_{c!=r} exp(2*f_r.f_c)) - 2*f_r.f_pos(r) ) ] / N^2
// v9 = v8 with __launch_bounds__(512, 2): the 2nd arg empirically acts as
// min-workgroups/CU -> (512,4) capped VGPRs at 64 and caused catastrophic
// scratch spill. (512,2) -> 128-VGPR cap, live state ~116 fits, no spill.
// Upper-triangle symmetric halving + frag-panel coalesced staging retained.

#define B_ROWS 4096
#define DIM 256
#define NTOT 8192
#define NTILEBLK 32      // 32 tiles of 256 -> slots
#define TILE_COLS 64
#define NTILE 4          // 4 x 64 cols = 256-col tile
#define SCALE_IN 1.69864360f   // sqrt(2*log2(e)): acc = 2*log2e*dot, exp2(acc)=exp(2 dot)

typedef int i32x4 __attribute__((ext_vector_type(4)));
typedef int i32x8 __attribute__((ext_vector_type(8)));
typedef float f32x16 __attribute__((ext_vector_type(16)));
typedef __attribute__((address_space(1))) const unsigned int gas_uint;
typedef __attribute__((address_space(3))) unsigned int las_uint;

__device__ __forceinline__ float wave_reduce_add(float v) {
#pragma unroll
    for (int m = 1; m < 64; m <<= 1) v += __shfl_xor(v, m, 64);
    return v;
}

// Fragment-panel layout: panel = row>>6 (16KB each). Within panel, 16B chunk
// index = ks*256 + cblk*128 + h*64 + l, where row = cblk*32 + (l&31),
// k = ks*64 + (l>>5)*32 + h*16. Serves LDS staging (linear copy), A-frags,
// and B-frags identically (sim = F*F^T: both operands are F rows).

// K1: 4 waves/block, one row-pair per wave. Normalize (fp32), write fp8 feats
// (scaled by SCALE_IN) into fragment-panel layout; exact fp32 positive sims.
__global__ __launch_bounds__(256) void k_norm(const float* __restrict__ zi,
                                              const float* __restrict__ zj,
                                              unsigned char* __restrict__ F8,
                                              float* __restrict__ pos_sim) {
    const int wave = threadIdx.x >> 6;
    const int lane = threadIdx.x & 63;
    const int r = blockIdx.x * 4 + wave;
    const float4 vi = reinterpret_cast<const float4*>(zi + (size_t)r * DIM)[lane];
    const float4 vj = reinterpret_cast<const float4*>(zj + (size_t)r * DIM)[lane];
    float si = vi.x * vi.x + vi.y * vi.y + vi.z * vi.z + vi.w * vi.w;
    float sj = vj.x * vj.x + vj.y * vj.y + vj.z * vj.z + vj.w * vj.w;
    si = wave_reduce_add(si);
    sj = wave_reduce_add(sj);
    const float ri = SCALE_IN / sqrtf(si);
    const float rj = SCALE_IN / sqrtf(sj);
    const float a0 = vi.x * ri, a1 = vi.y * ri, a2 = vi.z * ri, a3 = vi.w * ri;
    const float b0 = vj.x * rj, b1 = vj.y * rj, b2 = vj.z * rj, b3 = vj.w * rj;
    const float inv2 = 1.0f / (SCALE_IN * SCALE_IN);
    float dot = (a0 * b0 + a1 * b1 + a2 * b2 + a3 * b3) * inv2;
    dot = wave_reduce_add(dot);
    int pa = __builtin_amdgcn_cvt_pk_fp8_f32(a0, a1, 0, false);
    pa = __builtin_amdgcn_cvt_pk_fp8_f32(a2, a3, pa, true);
    int pb = __builtin_amdgcn_cvt_pk_fp8_f32(b0, b1, 0, false);
    pb = __builtin_amdgcn_cvt_pk_fp8_f32(b2, b3, pb, true);
    // this lane holds k = lane*4 .. lane*4+3 of its row -> frag address:
    const int ks = lane >> 4;
    const int k32 = (lane >> 3) & 1;
    const int h = (lane >> 2) & 1;
    const int b4 = (lane & 3) * 4;
    const size_t inner = (size_t)ks * 4096 + h * 1024 + 32 * k32 * 16 + b4;
    {
        const size_t addr = (size_t)(r >> 6) * 16384 + ((r >> 5) & 1) * 2048
                            + (r & 31) * 16 + inner;
        *reinterpret_cast<int*>(F8 + addr) = pa;
    }
    {
        const int r2 = r + B_ROWS;
        const size_t addr = (size_t)(r2 >> 6) * 16384 + ((r2 >> 5) & 1) * 2048
                            + (r2 & 31) * 16 + inner;
        *reinterpret_cast<int*>(F8 + addr) = pb;
    }
    if (lane == 0) {
        const float ps = 2.0f * dot;
        pos_sim[r] = ps;
        pos_sim[r + B_ROWS] = ps;
    }
}

// K2: upper-triangle tile (i,j), 256x256 per block. 8 waves x 32 rows.
// Row-sums -> Spart[j][rows of i]; col-sums (off-diag) -> Spart[i][cols of j].
__global__ __launch_bounds__(512, 2) void k_simsum(const unsigned char* __restrict__ F8,
                                                   float* __restrict__ Spart) {
    __shared__ unsigned char Bsm[2][16384];
    // triangular decode (uniform scalar)
    int rem = blockIdx.x, ti = 0;
    while (rem >= NTILEBLK - ti) { rem -= NTILEBLK - ti; ++ti; }
    const int tj = ti + rem;
    const bool isdiag = (ti == tj);

    const int tid = threadIdx.x;
    const int wave = tid >> 6;
    const int lane = tid & 63;
    const int c32 = lane & 31;
    const int l5 = lane >> 5;

    const int wrow0 = ti * 256 + wave * 32;
    const int col0 = tj * 256;

    // A fragments (frag-panel layout, coalesced): row = wrow0 + c32
    i32x8 a[4];
    {
        const unsigned char* apan = F8 + (size_t)(wrow0 >> 6) * 16384
                                    + ((wrow0 >> 5) & 1) * 2048 + lane * 16;
#pragma unroll
        for (int ks = 0; ks < 4; ++ks) {
            const i32x4 lo = *reinterpret_cast<const i32x4*>(apan + ks * 4096);
            const i32x4 hi = *reinterpret_cast<const i32x4*>(apan + ks * 4096 + 1024);
            a[ks] = __builtin_shufflevector(lo, hi, 0, 1, 2, 3, 4, 5, 6, 7);
        }
    }

    // stage tile t: contiguous 16KB panel copy (1024 chunks / 512 thr)
    auto stage = [&](int buf, int t) {
        const unsigned char* src = F8 + (size_t)(tj * 4 + t) * 16384;
#pragma unroll
        for (int i2 = 0; i2 < 2; ++i2) {
            __builtin_amdgcn_global_load_lds((gas_uint*)(src + (i2 * 512 + tid) * 16),
                                             (las_uint*)(&Bsm[buf][(i2 * 512 + wave * 64) * 16]),
                                             16, 0, 0);
        }
    };

    float sums[16];
#pragma unroll
    for (int g = 0; g < 16; ++g) sums[g] = 0.0f;
    float csum[NTILE][2];
#pragma unroll
    for (int t = 0; t < NTILE; ++t) { csum[t][0] = 0.0f; csum[t][1] = 0.0f; }

    stage(0, 0);
    asm volatile("s_waitcnt vmcnt(0)");
    __syncthreads();

#pragma unroll
    for (int t = 0; t < NTILE; ++t) {
        const int buf = t & 1;
        if (t + 1 < NTILE) stage(buf ^ 1, t + 1);

        f32x16 acc0 = {};
        f32x16 acc1 = {};
#pragma unroll
        for (int ks = 0; ks < 4; ++ks) {
            const unsigned char* base = &Bsm[buf][ks * 4096 + lane * 16];
            const i32x8 b0 = __builtin_shufflevector(
                *reinterpret_cast<const i32x4*>(base),
                *reinterpret_cast<const i32x4*>(base + 1024), 0, 1, 2, 3, 4, 5, 6, 7);
            const i32x8 b1 = __builtin_shufflevector(
                *reinterpret_cast<const i32x4*>(base + 2048),
                *reinterpret_cast<const i32x4*>(base + 3072), 0, 1, 2, 3, 4, 5, 6, 7);
            acc0 = __builtin_amdgcn_mfma_scale_f32_32x32x64_f8f6f4(
                a[ks], b0, acc0, 0, 0, 0, 0x7F7F7F7F, 0, 0x7F7F7F7F);
            acc1 = __builtin_amdgcn_mfma_scale_f32_32x32x64_f8f6f4(
                a[ks], b1, acc1, 0, 0, 0, 0x7F7F7F7F, 0, 0x7F7F7F7F);
        }

        const int cb = col0 + t * TILE_COLS;
        const bool d0 = isdiag && (wrow0 == cb);
        const bool d1 = isdiag && (wrow0 == cb + 32);
#pragma unroll
        for (int g = 0; g < 16; ++g) {
            const int rowid = (g & 3) + 8 * (g >> 2) + 4 * l5;
            float e0 = exp2f(acc0[g]);
            float e1 = exp2f(acc1[g]);
            if (d0 && rowid == c32) e0 = 0.0f;
            if (d1 && rowid == c32) e1 = 0.0f;
            sums[g] += e0 + e1;
            csum[t][0] += e0;
            csum[t][1] += e1;
        }

        asm volatile("s_waitcnt vmcnt(0)");
        __syncthreads();
    }

    // row-sums: fold across the 32 lanes holding each row's columns
#pragma unroll
    for (int g = 0; g < 16; ++g) {
        float s = sums[g];
        s += __shfl_xor(s, 1, 64);
        s += __shfl_xor(s, 2, 64);
        s += __shfl_xor(s, 4, 64);
        s += __shfl_xor(s, 8, 64);
        s += __shfl_xor(s, 16, 64);
        if (c32 == 0) {
            const int row = wrow0 + (g & 3) + 8 * (g >> 2) + 4 * l5;
            Spart[(size_t)tj * NTOT + row] = s;
        }
    }

    // col-sums (off-diag): fold l5 halves, reduce across 8 waves via LDS
    if (!isdiag) {
        float* cl = reinterpret_cast<float*>(&Bsm[0][0]);   // [8][256] floats
#pragma unroll
        for (int t = 0; t < NTILE; ++t) {
            const float c0f = csum[t][0] + __shfl_xor(csum[t][0], 32, 64);
            const float c1f = csum[t][1] + __shfl_xor(csum[t][1], 32, 64);
            const float v = (l5 == 0) ? c0f : c1f;
            cl[wave * 256 + t * 64 + l5 * 32 + c32] = v;
        }
        __syncthreads();
        if (tid < 256) {
            float tot = 0.0f;
#pragma unroll
            for (int w = 0; w < 8; ++w) tot += cl[w * 256 + tid];
            Spart[(size_t)ti * NTOT + col0 + tid] = tot;
        }
    }
}

// K3a: 32 blocks x 256 thr, one row each: S = sum slots, local = log(S)-pos.
__global__ __launch_bounds__(256) void k_reduce(const float* __restrict__ Spart,
                                                const float* __restrict__ pos_sim,
                                                float* __restrict__ Bpart) {
    __shared__ float red[4];
    const int r = blockIdx.x * 256 + threadIdx.x;
    float s = 0.0f;
#pragma unroll
    for (int c = 0; c < NTILEBLK; ++c) s += Spart[(size_t)c * NTOT + r];
    float local = logf(s) - pos_sim[r];
    local = wave_reduce_add(local);
    if ((threadIdx.x & 63) == 0) red[threadIdx.x >> 6] = local;
    __syncthreads();
    if (threadIdx.x == 0) Bpart[blockIdx.x] = red[0] + red[1] + red[2] + red[3];
}

// K3b: single wave folds 32 block partials.
__global__ void k_fin(const float* __restrict__ Bpart, float* __restrict__ out) {
    float v = (threadIdx.x < 32) ? Bpart[threadIdx.x] : 0.0f;
    v = wave_reduce_add(v);
    if (threadIdx.x == 0) out[0] = v / ((float)NTOT * (float)NTOT);
}

extern "C" void kernel_launch(void* const* d_in, const int* in_sizes, int n_in,
                              void* d_out, int out_size, void* d_ws, size_t ws_size,
                              hipStream_t stream) {
    (void)in_sizes; (void)n_in; (void)out_size; (void)ws_size;
    const float* zi = (const float*)d_in[0];
    const float* zj = (const float*)d_in[1];
    float* out = (float*)d_out;

    char* ws = (char*)d_ws;
    unsigned char* F8 = (unsigned char*)ws;                     // 2 MiB fp8 feats, frag-panel order
    float* pos_sim = (float*)(ws + 2097152);                    // 32 KiB
    float* Spart = (float*)(ws + 2097152 + 65536);              // 1 MiB (32 slots x 8192)
    float* Bpart = (float*)(ws + 2097152 + 65536 + 1048576);    // 128 B

    k_norm<<<B_ROWS / 4, 256, 0, stream>>>(zi, zj, F8, pos_sim);
    k_simsum<<<(NTILEBLK * (NTILEBLK + 1)) / 2, 512, 0, stream>>>(F8, Spart);
    k_reduce<<<NTOT / 256, 256, 0, stream>>>(Spart, pos_sim, Bpart);
    k_fin<<<1, 64, 0, stream>>>(Bpart, out);
}

// Round 10
// 46.454 us; speedup vs baseline: 8.0277x; 1.0823x over previous
//
#include <hip/hip_runtime.h>

// NT-Xent loss, B=4096, D=256, N=8192, T=0.5
// loss = [ sum_r ( log(sum_{c!=r} exp(2*f_r.f_c)) - 2*f_r.f_pos(r) ) ] / N^2
// v10: v6 geometry (512 blocks exactly = one co-residency round, 8 tiles) +
// frag-panel F8 layout (contiguous coalesced staging) + counted-vmcnt 3-deep
// pipeline (4 LDS bufs, vmcnt(4) steady, raw s_barrier, never drain in loop)
// + setprio around MFMA. __launch_bounds__(512,2) -> 128-VGPR cap (arg2 is
// workgroups/CU empirically; (512,4)'s 64-cap caused v7/v8 spills).

#define B_ROWS 4096
#define DIM 256
#define NTOT 8192
#define NCHUNK 16        // col chunks of 512
#define CHUNK_COLS 512
#define TILE_COLS 64
#define NTILE 8
#define BLK_ROWS 256
#define SCALE_IN 1.69864360f   // sqrt(2*log2(e)): acc = 2*log2e*dot, exp2(acc)=exp(2 dot)

typedef int i32x4 __attribute__((ext_vector_type(4)));
typedef int i32x8 __attribute__((ext_vector_type(8)));
typedef float f32x16 __attribute__((ext_vector_type(16)));
typedef __attribute__((address_space(1))) const unsigned int gas_uint;
typedef __attribute__((address_space(3))) unsigned int las_uint;

__device__ __forceinline__ float wave_reduce_add(float v) {
#pragma unroll
    for (int m = 1; m < 64; m <<= 1) v += __shfl_xor(v, m, 64);
    return v;
}

// Fragment-panel layout: panel = row>>6 (16KB each). Within panel, 16B chunk
// index = ks*256 + cblk*128 + h*64 + l, where row = cblk*32 + (l&31),
// k = ks*64 + (l>>5)*32 + h*16. Staging = linear 16KB copy; A/B frag reads
// are lane*16-stride (conflict-free).

// K1: 4 waves/block, one row-pair per wave. Normalize (fp32), write fp8 feats
// (scaled by SCALE_IN) into fragment-panel layout; exact fp32 positive sims.
__global__ __launch_bounds__(256) void k_norm(const float* __restrict__ zi,
                                              const float* __restrict__ zj,
                                              unsigned char* __restrict__ F8,
                                              float* __restrict__ pos_sim) {
    const int wave = threadIdx.x >> 6;
    const int lane = threadIdx.x & 63;
    const int r = blockIdx.x * 4 + wave;
    const float4 vi = reinterpret_cast<const float4*>(zi + (size_t)r * DIM)[lane];
    const float4 vj = reinterpret_cast<const float4*>(zj + (size_t)r * DIM)[lane];
    float si = vi.x * vi.x + vi.y * vi.y + vi.z * vi.z + vi.w * vi.w;
    float sj = vj.x * vj.x + vj.y * vj.y + vj.z * vj.z + vj.w * vj.w;
    si = wave_reduce_add(si);
    sj = wave_reduce_add(sj);
    const float ri = SCALE_IN / sqrtf(si);
    const float rj = SCALE_IN / sqrtf(sj);
    const float a0 = vi.x * ri, a1 = vi.y * ri, a2 = vi.z * ri, a3 = vi.w * ri;
    const float b0 = vj.x * rj, b1 = vj.y * rj, b2 = vj.z * rj, b3 = vj.w * rj;
    const float inv2 = 1.0f / (SCALE_IN * SCALE_IN);
    float dot = (a0 * b0 + a1 * b1 + a2 * b2 + a3 * b3) * inv2;
    dot = wave_reduce_add(dot);
    int pa = __builtin_amdgcn_cvt_pk_fp8_f32(a0, a1, 0, false);
    pa = __builtin_amdgcn_cvt_pk_fp8_f32(a2, a3, pa, true);
    int pb = __builtin_amdgcn_cvt_pk_fp8_f32(b0, b1, 0, false);
    pb = __builtin_amdgcn_cvt_pk_fp8_f32(b2, b3, pb, true);
    // this lane holds k = lane*4 .. lane*4+3 of its row -> frag address:
    const int ks = lane >> 4;
    const int k32 = (lane >> 3) & 1;
    const int h = (lane >> 2) & 1;
    const int b4 = (lane & 3) * 4;
    const size_t inner = (size_t)ks * 4096 + h * 1024 + 32 * k32 * 16 + b4;
    {
        const size_t addr = (size_t)(r >> 6) * 16384 + ((r >> 5) & 1) * 2048
                            + (r & 31) * 16 + inner;
        *reinterpret_cast<int*>(F8 + addr) = pa;
    }
    {
        const int r2 = r + B_ROWS;
        const size_t addr = (size_t)(r2 >> 6) * 16384 + ((r2 >> 5) & 1) * 2048
                            + (r2 & 31) * 16 + inner;
        *reinterpret_cast<int*>(F8 + addr) = pb;
    }
    if (lane == 0) {
        const float ps = 2.0f * dot;
        pos_sim[r] = ps;
        pos_sim[r + B_ROWS] = ps;
    }
}

// K2: MX-fp8 sim GEMM (32x32x64, unit scales) + fused exp2 row-sum.
// 8 waves x 32 rows x 512 cols; 4x16KB LDS bufs, 3-deep counted-vmcnt pipe.
__global__ __launch_bounds__(512, 2) void k_simsum(const unsigned char* __restrict__ F8,
                                                   float* __restrict__ Spart) {
    __shared__ unsigned char Bsm[4][16384];
    const int bid0 = blockIdx.x;
    const int bid = (bid0 & 7) * 64 + (bid0 >> 3);   // XCD: 2 col-chunks per XCD
    const int ch = bid >> 5;
    const int rt = bid & 31;
    const int tid = threadIdx.x;
    const int wave = tid >> 6;
    const int lane = tid & 63;
    const int c32 = lane & 31;
    const int l5 = lane >> 5;

    const int wrow0 = rt * BLK_ROWS + wave * 32;
    const int col0 = ch * CHUNK_COLS;

    // A fragments (frag-panel, coalesced) -- issued FIRST so vmcnt(4) at
    // step 0 covers them (8 A-loads + stage0's 2 complete; 4 stay in flight).
    i32x8 a[4];
    {
        const unsigned char* apan = F8 + (size_t)(wrow0 >> 6) * 16384
                                    + ((wrow0 >> 5) & 1) * 2048 + lane * 16;
#pragma unroll
        for (int ks = 0; ks < 4; ++ks) {
            const i32x4 lo = *reinterpret_cast<const i32x4*>(apan + ks * 4096);
            const i32x4 hi = *reinterpret_cast<const i32x4*>(apan + ks * 4096 + 1024);
            a[ks] = __builtin_shufflevector(lo, hi, 0, 1, 2, 3, 4, 5, 6, 7);
        }
    }
    __builtin_amdgcn_sched_barrier(0);

    // stage tile t (panel ch*8+t, contiguous 16KB) into buffer buf
    auto stage = [&](int buf, int t) {
        const unsigned char* src = F8 + (size_t)(ch * 8 + t) * 16384;
#pragma unroll
        for (int i2 = 0; i2 < 2; ++i2) {
            __builtin_amdgcn_global_load_lds((gas_uint*)(src + (i2 * 512 + tid) * 16),
                                             (las_uint*)(&Bsm[buf][(i2 * 512 + wave * 64) * 16]),
                                             16, 0, 0);
        }
    };

    float sums[16];
#pragma unroll
    for (int g = 0; g < 16; ++g) sums[g] = 0.0f;

    stage(0, 0);
    stage(1, 1);
    stage(2, 2);
    __builtin_amdgcn_sched_barrier(0);

    auto compute = [&](int t) {
        const int buf = t & 3;
        f32x16 acc0 = {};
        f32x16 acc1 = {};
        __builtin_amdgcn_s_setprio(1);
#pragma unroll
        for (int ks = 0; ks < 4; ++ks) {
            const unsigned char* base = &Bsm[buf][ks * 4096 + lane * 16];
            const i32x8 b0 = __builtin_shufflevector(
                *reinterpret_cast<const i32x4*>(base),
                *reinterpret_cast<const i32x4*>(base + 1024), 0, 1, 2, 3, 4, 5, 6, 7);
            const i32x8 b1 = __builtin_shufflevector(
                *reinterpret_cast<const i32x4*>(base + 2048),
                *reinterpret_cast<const i32x4*>(base + 3072), 0, 1, 2, 3, 4, 5, 6, 7);
            acc0 = __builtin_amdgcn_mfma_scale_f32_32x32x64_f8f6f4(
                a[ks], b0, acc0, 0, 0, 0, 0x7F7F7F7F, 0, 0x7F7F7F7F);
            acc1 = __builtin_amdgcn_mfma_scale_f32_32x32x64_f8f6f4(
                a[ks], b1, acc1, 0, 0, 0, 0x7F7F7F7F, 0, 0x7F7F7F7F);
        }
        __builtin_amdgcn_s_setprio(0);

        const int cb = col0 + t * TILE_COLS;
        const bool d0 = (wrow0 == cb);
        const bool d1 = (wrow0 == cb + 32);
        if (d0 | d1) {
#pragma unroll
            for (int g = 0; g < 16; ++g) {
                const int rowid = (g & 3) + 8 * (g >> 2) + 4 * l5;
                float e0 = exp2f(acc0[g]);
                float e1 = exp2f(acc1[g]);
                if (d0 && rowid == c32) e0 = 0.0f;
                if (d1 && rowid == c32) e1 = 0.0f;
                sums[g] += e0 + e1;
            }
        } else {
#pragma unroll
            for (int g = 0; g < 16; ++g)
                sums[g] += exp2f(acc0[g]) + exp2f(acc1[g]);
        }
    };

    // steady state: wait ONLY the oldest stage (2 newer stay in flight),
    // raw barrier (no compiler vmcnt(0) drain), compute, stage 3 ahead.
    // Buffer staged at step t ((t+3)&3) was last read at step t-1 -- its
    // readers' ds_reads completed before their MFMAs, which precede this
    // barrier => write-after-read safe.
#define STEP(T, N)                                              \
    do {                                                        \
        __builtin_amdgcn_sched_barrier(0);                      \
        asm volatile("s_waitcnt vmcnt(" #N ")");                \
        __builtin_amdgcn_s_barrier();                           \
        __builtin_amdgcn_sched_barrier(0);                      \
        compute(T);                                             \
        if ((T) + 3 < NTILE) stage(((T) + 3) & 3, (T) + 3);     \
    } while (0)

    STEP(0, 4);
    STEP(1, 4);
    STEP(2, 4);
    STEP(3, 4);
    STEP(4, 4);
    STEP(5, 4);
    STEP(6, 2);
    STEP(7, 0);
#undef STEP

    // reduce each row's partial across the 32 lanes holding its columns
#pragma unroll
    for (int g = 0; g < 16; ++g) {
        float s = sums[g];
        s += __shfl_xor(s, 1, 64);
        s += __shfl_xor(s, 2, 64);
        s += __shfl_xor(s, 4, 64);
        s += __shfl_xor(s, 8, 64);
        s += __shfl_xor(s, 16, 64);
        if (c32 == 0) {
            const int row = wrow0 + (g & 3) + 8 * (g >> 2) + 4 * l5;
            Spart[(size_t)ch * NTOT + row] = s;
        }
    }
}

// K3a: 32 blocks x 256 thr, one row each: S = sum chunks, local = log(S)-pos.
__global__ __launch_bounds__(256) void k_reduce(const float* __restrict__ Spart,
                                                const float* __restrict__ pos_sim,
                                                float* __restrict__ Bpart) {
    __shared__ float red[4];
    const int r = blockIdx.x * 256 + threadIdx.x;
    float s = 0.0f;
#pragma unroll
    for (int c = 0; c < NCHUNK; ++c) s += Spart[(size_t)c * NTOT + r];
    float local = logf(s) - pos_sim[r];
    local = wave_reduce_add(local);
    if ((threadIdx.x & 63) == 0) red[threadIdx.x >> 6] = local;
    __syncthreads();
    if (threadIdx.x == 0) Bpart[blockIdx.x] = red[0] + red[1] + red[2] + red[3];
}

// K3b: single wave folds 32 block partials.
__global__ void k_fin(const float* __restrict__ Bpart, float* __restrict__ out) {
    float v = (threadIdx.x < 32) ? Bpart[threadIdx.x] : 0.0f;
    v = wave_reduce_add(v);
    if (threadIdx.x == 0) out[0] = v / ((float)NTOT * (float)NTOT);
}

extern "C" void kernel_launch(void* const* d_in, const int* in_sizes, int n_in,
                              void* d_out, int out_size, void* d_ws, size_t ws_size,
                              hipStream_t stream) {
    (void)in_sizes; (void)n_in; (void)out_size; (void)ws_size;
    const float* zi = (const float*)d_in[0];
    const float* zj = (const float*)d_in[1];
    float* out = (float*)d_out;

    char* ws = (char*)d_ws;
    unsigned char* F8 = (unsigned char*)ws;                     // 2 MiB fp8 feats, frag-panel order
    float* pos_sim = (float*)(ws + 2097152);                    // 32 KiB
    float* Spart = (float*)(ws + 2097152 + 65536);              // 512 KiB (16 chunks)
    float* Bpart = (float*)(ws + 2097152 + 65536 + 524288);     // 128 B

    k_norm<<<B_ROWS / 4, 256, 0, stream>>>(zi, zj, F8, pos_sim);
    k_simsum<<<512, 512, 0, stream>>>(F8, Spart);
    k_reduce<<<NTOT / 256, 256, 0, stream>>>(Spart, pos_sim, Bpart);
    k_fin<<<1, 64, 0, stream>>>(Bpart, out);
}

// Round 11
// 36.494 us; speedup vs baseline: 10.2188x; 1.2729x over previous
//
#include <hip/hip_runtime.h>

// NT-Xent loss, B=4096, D=256, N=8192, T=0.5
// loss = [ sum_r ( log(sum_{c!=r} exp(2*f_r.f_c)) - 2*f_r.f_pos(r) ) ] / N^2
// v11: MX-fp4 (e2m1, cbsz=blgp=4) with scale bytes 2^-4 both sides:
// q ~ f*16*SCALE_IN on the e2m1 grid, HW scales give acc = 2*log2e*dot.
// Halves MFMA time, halves LDS bytes (1 ds_read_b128 per operand, no
// i32x8-assembly movs), halves staging. 256-thr blocks, 4 blocks/CU.
// v6's proven 2-phase dbuf; frag-panel F4 layout (linear coalesced staging).

#define B_ROWS 4096
#define DIM 256
#define NTOT 8192
#define NCHUNK 16        // col chunks of 512
#define CHUNK_COLS 512
#define TILE_COLS 64
#define NTILE 8
#define BLK_ROWS 128     // 4 waves * 32 rows
#define SCALE_IN 1.69864360f   // sqrt(2*log2(e))
#define QS (16.0f * SCALE_IN)  // fp4 pre-scale; MFMA scales 2^-4 * 2^-4 undo 256x

typedef int i32x4 __attribute__((ext_vector_type(4)));
typedef int i32x8 __attribute__((ext_vector_type(8)));
typedef float f32x16 __attribute__((ext_vector_type(16)));
typedef __attribute__((address_space(1))) const unsigned int gas_uint;
typedef __attribute__((address_space(3))) unsigned int las_uint;

__device__ __forceinline__ float wave_reduce_add(float v) {
#pragma unroll
    for (int m = 1; m < 64; m <<= 1) v += __shfl_xor(v, m, 64);
    return v;
}

__device__ __forceinline__ i32x8 pad8(i32x4 v) {
    return __builtin_shufflevector(v, v, 0, 1, 2, 3, -1, -1, -1, -1);
}

// fp4 e2m1 encode, values {0,.5,1,1.5,2,3,4,6}, round-to-nearest
__device__ __forceinline__ unsigned fp4_enc(float x) {
    const unsigned s = (x < 0.0f) ? 8u : 0u;
    const float v = fabsf(x);
    unsigned c;
    if (v < 1.25f) {
        c = (v < 0.25f) ? 0u : (v < 0.75f) ? 1u : 2u;
    } else if (v < 2.5f) {
        c = (v < 1.75f) ? 3u : 4u;
    } else {
        c = (v < 3.5f) ? 5u : (v < 5.0f) ? 6u : 7u;
    }
    return s | c;
}

// F4 fragment-panel layout: panel = row>>6 (8KB each). 16B chunk index
// q = ks*128 + ((row>>5)&1)*64 + (l>>5)*32 + (row&31) holds 32 k-elems
// (k = ks*64 + (l>>5)*32 ..) of one row. Staging = linear 8KB copy;
// A/B frag reads are lane*16-stride (conflict-free).

// K1: 4 waves/block, one row-pair per wave. Normalize (fp32), quantize to
// fp4*QS into frag-panel layout; exact fp32 positive sims.
__global__ __launch_bounds__(256) void k_norm(const float* __restrict__ zi,
                                              const float* __restrict__ zj,
                                              unsigned char* __restrict__ F4,
                                              float* __restrict__ pos_sim) {
    const int wave = threadIdx.x >> 6;
    const int lane = threadIdx.x & 63;
    const int r = blockIdx.x * 4 + wave;
    const float4 vi = reinterpret_cast<const float4*>(zi + (size_t)r * DIM)[lane];
    const float4 vj = reinterpret_cast<const float4*>(zj + (size_t)r * DIM)[lane];
    float si = vi.x * vi.x + vi.y * vi.y + vi.z * vi.z + vi.w * vi.w;
    float sj = vj.x * vj.x + vj.y * vj.y + vj.z * vj.z + vj.w * vj.w;
    si = wave_reduce_add(si);
    sj = wave_reduce_add(sj);
    const float ri = QS / sqrtf(si);
    const float rj = QS / sqrtf(sj);
    const float a0 = vi.x * ri, a1 = vi.y * ri, a2 = vi.z * ri, a3 = vi.w * ri;
    const float b0 = vj.x * rj, b1 = vj.y * rj, b2 = vj.z * rj, b3 = vj.w * rj;
    const float inv2 = 1.0f / (QS * QS);
    float dot = (a0 * b0 + a1 * b1 + a2 * b2 + a3 * b3) * inv2;
    dot = wave_reduce_add(dot);
    const unsigned short pka = (unsigned short)(fp4_enc(a0) | (fp4_enc(a1) << 4) |
                                                (fp4_enc(a2) << 8) | (fp4_enc(a3) << 12));
    const unsigned short pkb = (unsigned short)(fp4_enc(b0) | (fp4_enc(b1) << 4) |
                                                (fp4_enc(b2) << 8) | (fp4_enc(b3) << 12));
    // lane holds k = lane*4..lane*4+3: ks = lane>>4, k-half = (lane>>3)&1,
    // byte-in-chunk = (lane&7)*2
    const int ks = lane >> 4;
    const int l5 = (lane >> 3) & 1;
    const int byt = (lane & 7) * 2;
    {
        const size_t addr = (size_t)(r >> 6) * 8192
                            + (size_t)(ks * 128 + ((r >> 5) & 1) * 64 + l5 * 32 + (r & 31)) * 16
                            + byt;
        *reinterpret_cast<unsigned short*>(F4 + addr) = pka;
    }
    {
        const int r2 = r + B_ROWS;
        const size_t addr = (size_t)(r2 >> 6) * 8192
                            + (size_t)(ks * 128 + ((r2 >> 5) & 1) * 64 + l5 * 32 + (r2 & 31)) * 16
                            + byt;
        *reinterpret_cast<unsigned short*>(F4 + addr) = pkb;
    }
    if (lane == 0) {
        const float ps = 2.0f * dot;
        pos_sim[r] = ps;
        pos_sim[r + B_ROWS] = ps;
    }
}

// K2: MX-fp4 sim GEMM (32x32x64, scales 2^-4) + fused exp2 row-sum.
// 4 waves x 32 rows x 512 cols; 2-phase dbuf (2 x 8KB), 4 blocks/CU.
__global__ __launch_bounds__(256, 4) void k_simsum(const unsigned char* __restrict__ F4,
                                                   float* __restrict__ Spart) {
    __shared__ unsigned char Bsm[2][8192];
    const int bid0 = blockIdx.x;
    const int bid = (bid0 & 7) * 128 + (bid0 >> 3);   // XCD: 2 col-chunks per XCD
    const int ch = bid >> 6;   // 16 chunks of 512 cols
    const int rt = bid & 63;   // 64 row tiles of 128
    const int tid = threadIdx.x;
    const int wave = tid >> 6;
    const int lane = tid & 63;
    const int c32 = lane & 31;
    const int l5 = lane >> 5;

    const int wrow0 = rt * BLK_ROWS + wave * 32;
    const int col0 = ch * CHUNK_COLS;

    // A fragments (frag-panel, coalesced 16B/lane): 4 ks x i32x4
    i32x4 a[4];
    {
        const unsigned char* apan = F4 + (size_t)(wrow0 >> 6) * 8192
                                    + (size_t)(((wrow0 >> 5) & 1) * 64 + lane) * 16;
#pragma unroll
        for (int ks = 0; ks < 4; ++ks)
            a[ks] = *reinterpret_cast<const i32x4*>(apan + ks * 2048);
    }

    // stage tile t (panel ch*8+t, contiguous 8KB) into buf; 2 chunks/thread
    auto stage = [&](int buf, int t) {
        const unsigned char* src = F4 + (size_t)(ch * 8 + t) * 8192;
#pragma unroll
        for (int i2 = 0; i2 < 2; ++i2) {
            __builtin_amdgcn_global_load_lds((gas_uint*)(src + (i2 * 256 + tid) * 16),
                                             (las_uint*)(&Bsm[buf][(i2 * 256 + wave * 64) * 16]),
                                             16, 0, 0);
        }
    };

    float sums[16];
#pragma unroll
    for (int g = 0; g < 16; ++g) sums[g] = 0.0f;

    stage(0, 0);
    asm volatile("s_waitcnt vmcnt(0)");
    __syncthreads();

    for (int t = 0; t < NTILE; ++t) {
        const int buf = t & 1;
        if (t + 1 < NTILE) stage(buf ^ 1, t + 1);

        f32x16 acc0 = {};
        f32x16 acc1 = {};
#pragma unroll
        for (int ks = 0; ks < 4; ++ks) {
            const unsigned char* base = &Bsm[buf][ks * 2048 + lane * 16];
            const i32x4 b0 = *reinterpret_cast<const i32x4*>(base);
            const i32x4 b1 = *reinterpret_cast<const i32x4*>(base + 1024);
            acc0 = __builtin_amdgcn_mfma_scale_f32_32x32x64_f8f6f4(
                pad8(a[ks]), pad8(b0), acc0, 4, 4, 0, 0x7B7B7B7B, 0, 0x7B7B7B7B);
            acc1 = __builtin_amdgcn_mfma_scale_f32_32x32x64_f8f6f4(
                pad8(a[ks]), pad8(b1), acc1, 4, 4, 0, 0x7B7B7B7B, 0, 0x7B7B7B7B);
        }

        const int cb = col0 + t * TILE_COLS;
        const bool d0 = (wrow0 == cb);
        const bool d1 = (wrow0 == cb + 32);
        if (d0 | d1) {
#pragma unroll
            for (int g = 0; g < 16; ++g) {
                const int rowid = (g & 3) + 8 * (g >> 2) + 4 * l5;
                float e0 = exp2f(acc0[g]);
                float e1 = exp2f(acc1[g]);
                if (d0 && rowid == c32) e0 = 0.0f;
                if (d1 && rowid == c32) e1 = 0.0f;
                sums[g] += e0 + e1;
            }
        } else {
#pragma unroll
            for (int g = 0; g < 16; ++g)
                sums[g] += exp2f(acc0[g]) + exp2f(acc1[g]);
        }

        asm volatile("s_waitcnt vmcnt(0)");
        __syncthreads();
    }

    // reduce each row's partial across the 32 lanes holding its columns
#pragma unroll
    for (int g = 0; g < 16; ++g) {
        float s = sums[g];
        s += __shfl_xor(s, 1, 64);
        s += __shfl_xor(s, 2, 64);
        s += __shfl_xor(s, 4, 64);
        s += __shfl_xor(s, 8, 64);
        s += __shfl_xor(s, 16, 64);
        if (c32 == 0) {
            const int row = wrow0 + (g & 3) + 8 * (g >> 2) + 4 * l5;
            Spart[(size_t)ch * NTOT + row] = s;
        }
    }
}

// K3a: 32 blocks x 256 thr, one row each: S = sum chunks, local = log(S)-pos.
__global__ __launch_bounds__(256) void k_reduce(const float* __restrict__ Spart,
                                                const float* __restrict__ pos_sim,
                                                float* __restrict__ Bpart) {
    __shared__ float red[4];
    const int r = blockIdx.x * 256 + threadIdx.x;
    float s = 0.0f;
#pragma unroll
    for (int c = 0; c < NCHUNK; ++c) s += Spart[(size_t)c * NTOT + r];
    float local = logf(s) - pos_sim[r];
    local = wave_reduce_add(local);
    if ((threadIdx.x & 63) == 0) red[threadIdx.x >> 6] = local;
    __syncthreads();
    if (threadIdx.x == 0) Bpart[blockIdx.x] = red[0] + red[1] + red[2] + red[3];
}

// K3b: single wave folds 32 block partials.
__global__ void k_fin(const float* __restrict__ Bpart, float* __restrict__ out) {
    float v = (threadIdx.x < 32) ? Bpart[threadIdx.x] : 0.0f;
    v = wave_reduce_add(v);
    if (threadIdx.x == 0) out[0] = v / ((float)NTOT * (float)NTOT);
}

extern "C" void kernel_launch(void* const* d_in, const int* in_sizes, int n_in,
                              void* d_out, int out_size, void* d_ws, size_t ws_size,
                              hipStream_t stream) {
    (void)in_sizes; (void)n_in; (void)out_size; (void)ws_size;
    const float* zi = (const float*)d_in[0];
    const float* zj = (const float*)d_in[1];
    float* out = (float*)d_out;

    char* ws = (char*)d_ws;
    unsigned char* F4 = (unsigned char*)ws;                     // 1 MiB fp4 feats, frag-panel order
    float* pos_sim = (float*)(ws + 1048576);                    // 32 KiB
    float* Spart = (float*)(ws + 1048576 + 65536);              // 512 KiB (16 chunks)
    float* Bpart = (float*)(ws + 1048576 + 65536 + 524288);     // 128 B

    k_norm<<<B_ROWS / 4, 256, 0, stream>>>(zi, zj, F4, pos_sim);
    k_simsum<<<1024, 256, 0, stream>>>(F4, Spart);
    k_reduce<<<NTOT / 256, 256, 0, stream>>>(Spart, pos_sim, Bpart);
    k_fin<<<1, 64, 0, stream>>>(Bpart, out);
}